// Round 1
// baseline (878.989 us; speedup 1.0000x reference)
//
#include <hip/hip_runtime.h>

#define NBATCH 32
#define A_TOTAL 49104
#define PRE_N 6000
#define POST_N 300
#define NMS_T 0.7f
#define IMGF 512.0f

// ---------------------------------------------------------------------------
// Kernel 1: build sortable keys. key = (score_bits << 16) | (65535 - idx).
// Scores are uniform [0,1) (positive), so float bits are monotone as uint.
// Ascending sort => descending score with ties broken by LOWER index first
// when read from the back — exactly jax.lax.top_k order.
// ---------------------------------------------------------------------------
__global__ __launch_bounds__(256) void build_keys(const float* __restrict__ scores,
                                                  unsigned long long* __restrict__ keys) {
    int gid = blockIdx.x * 256 + threadIdx.x;
    if (gid >= NBATCH * A_TOTAL) return;
    int a = gid % A_TOTAL;
    unsigned int sb = __float_as_uint(scores[gid]);
    keys[gid] = ((unsigned long long)sb << 16) | (unsigned long long)(65535 - a);
}

// ---------------------------------------------------------------------------
// Kernel 2: one stable 4-bit LSD radix pass, one block per batch.
// 256 threads, each owns a contiguous chunk of 192 elements.
// Per-thread histograms live in LDS (column t) to avoid scratch (rule #20).
// ---------------------------------------------------------------------------
#define RT 256
#define RCHUNK 192

__global__ __launch_bounds__(256) void radix_pass(const unsigned long long* __restrict__ in,
                                                  unsigned long long* __restrict__ out,
                                                  int shift) {
    __shared__ unsigned int cnt[16 * RT];   // digit-major: cnt[d*RT + t]
    __shared__ unsigned int sums[RT];
    int b = blockIdx.x;
    const unsigned long long* __restrict__ src = in + (size_t)b * A_TOTAL;
    unsigned long long* __restrict__ dst = out + (size_t)b * A_TOTAL;
    int t = threadIdx.x;

#pragma unroll
    for (int d = 0; d < 16; ++d) cnt[d * RT + t] = 0;

    int start = t * RCHUNK;
    int end = min(start + RCHUNK, A_TOTAL);
    // histogram (each thread touches only column t — no races)
    for (int i = start; i < end; ++i) {
        int d = (int)((src[i] >> shift) & 15ULL);
        cnt[d * RT + t] += 1;
    }
    __syncthreads();

    // exclusive scan of the 4096 counters in linear (digit-major) order.
    // thread t scans entries [t*16, t*16+16).
    unsigned int vals[16];
    unsigned int run = 0;
#pragma unroll
    for (int q = 0; q < 16; ++q) vals[q] = cnt[t * 16 + q];
#pragma unroll
    for (int q = 0; q < 16; ++q) { unsigned int v = vals[q]; vals[q] = run; run += v; }
    sums[t] = run;
    unsigned int total = run;
    __syncthreads();
    for (int s = 1; s < RT; s <<= 1) {
        unsigned int v = 0;
        if (t >= s) v = sums[t - s];
        __syncthreads();
        sums[t] += v;
        __syncthreads();
    }
    unsigned int base = sums[t] - total;
#pragma unroll
    for (int q = 0; q < 16; ++q) cnt[t * 16 + q] = vals[q] + base;
    __syncthreads();

    // stable scatter: per-thread running offsets live in column t of cnt
    for (int i = start; i < end; ++i) {
        unsigned long long k = src[i];
        int d = (int)((k >> shift) & 15ULL);
        unsigned int pos = cnt[d * RT + t];
        cnt[d * RT + t] = pos + 1;
        dst[pos] = k;
    }
}

// ---------------------------------------------------------------------------
// Kernel 3: decode the top PRE_N boxes per batch (read sorted keys from the
// back). Anchor regenerated in f64 then cast to f32 (matches numpy ANCHORS),
// then f32 decode mirroring the reference op order.
// ---------------------------------------------------------------------------
__global__ __launch_bounds__(256) void decode_topk(const unsigned long long* __restrict__ sortedKeys,
                                                   const float4* __restrict__ deltas,
                                                   float4* __restrict__ boxes,
                                                   float* __restrict__ areas) {
    int gid = blockIdx.x * 256 + threadIdx.x;
    if (gid >= NBATCH * PRE_N) return;
    int b = gid / PRE_N;
    int r = gid % PRE_N;
    unsigned long long key = sortedKeys[(size_t)b * A_TOTAL + (A_TOTAL - 1 - r)];
    int idx = 65535 - (int)(key & 0xFFFFULL);

    // level decomposition: cum counts 36864, 46080, 48384, 48960, 49104
    int off, fs, stride, size;
    if (idx < 36864)      { off = 0;     fs = 64; stride = 8;   size = 32;  }
    else if (idx < 46080) { off = 36864; fs = 32; stride = 16;  size = 64;  }
    else if (idx < 48384) { off = 46080; fs = 16; stride = 32;  size = 128; }
    else if (idx < 48960) { off = 48384; fs = 8;  stride = 64;  size = 256; }
    else                  { off = 48960; fs = 4;  stride = 128; size = 512; }
    int loc = idx - off;
    int p = loc / 9, k = loc % 9;
    int iy = p / fs, jx = p % fs;
    int ks = k % 3, kr = k / 3;

    double scale = pow(2.0, (double)ks / 3.0);
    double ratio = (kr == 0) ? 0.5 : (kr == 1 ? 1.0 : 2.0);
    double ss = (double)size * scale;
    double area0 = ss * ss;
    double w = sqrt(area0 / ratio);
    double h = w * ratio;
    double cxs = ((double)jx + 0.5) * (double)stride;
    double cys = ((double)iy + 0.5) * (double)stride;
    float x1a = (float)(cxs - 0.5 * w);
    float x2a = (float)(cxs + 0.5 * w);
    float y1a = (float)(cys - 0.5 * h);
    float y2a = (float)(cys + 0.5 * h);

    // f32 decode, same op order as reference
    float wa = x2a - x1a;
    float ha = y2a - y1a;
    float cxa = x1a + 0.5f * wa;
    float cya = y1a + 0.5f * ha;
    float4 d = deltas[(size_t)b * A_TOTAL + idx];
    float dx = d.x * 0.1f, dy = d.y * 0.1f, dw = d.z * 0.2f, dh = d.w * 0.2f;
    float pcx = cxa + dx * wa;
    float pcy = cya + dy * ha;
    float pw = __expf(dw) * wa;   // fast exp could drift; use precise:
    pw = expf(dw) * wa;
    float ph = expf(dh) * ha;
    float bx1 = fminf(fmaxf(pcx - 0.5f * pw, 0.0f), IMGF);
    float by1 = fminf(fmaxf(pcy - 0.5f * ph, 0.0f), IMGF);
    float bx2 = fminf(fmaxf(pcx + 0.5f * pw, 0.0f), IMGF);
    float by2 = fminf(fmaxf(pcy + 0.5f * ph, 0.0f), IMGF);
    boxes[gid] = make_float4(bx1, by1, bx2, by2);
    areas[gid] = (bx2 - bx1) * (by2 - by1);
}

// ---------------------------------------------------------------------------
// Kernel 4: greedy NMS, one wave (64 lanes) per batch. Candidates iterated in
// sorted (descending score) order => identical to reference's argmax-scan.
// Lanes parallelize IoU checks against the already-selected set (LDS).
// Early exit at POST_N picks.
// ---------------------------------------------------------------------------
__global__ __launch_bounds__(64) void nms_kernel(const float4* __restrict__ boxes,
                                                 const float* __restrict__ areas,
                                                 float* __restrict__ out) {
    int b = blockIdx.x;
    const float4* __restrict__ bb = boxes + (size_t)b * PRE_N;
    const float* __restrict__ aa = areas + (size_t)b * PRE_N;
    float* __restrict__ o = out + (size_t)b * POST_N * 5;
    __shared__ float4 selB[POST_N];
    __shared__ float selA[POST_N];
    int lane = threadIdx.x;
    int nsel = 0;

    for (int i = 0; i < PRE_N && nsel < POST_N; ++i) {
        float4 c = bb[i];          // uniform across lanes
        float ac = aa[i];
        bool sup = false;
        for (int base = 0; base < nsel && !sup; base += 64) {
            int ti = base + lane;
            bool over = false;
            if (ti < nsel) {
                float4 s = selB[ti];
                float xx1 = fmaxf(c.x, s.x);
                float yy1 = fmaxf(c.y, s.y);
                float xx2 = fminf(c.z, s.z);
                float yy2 = fminf(c.w, s.w);
                float inter = fmaxf(xx2 - xx1, 0.0f) * fmaxf(yy2 - yy1, 0.0f);
                float iou = inter / (ac + selA[ti] - inter + 1e-8f);
                over = iou > NMS_T;
            }
            if (__any(over)) sup = true;
        }
        if (!sup) {
            if (lane == 0) {
                selB[nsel] = c;
                selA[nsel] = ac;
                o[nsel * 5 + 0] = (float)b;
                o[nsel * 5 + 1] = c.x;
                o[nsel * 5 + 2] = c.y;
                o[nsel * 5 + 3] = c.z;
                o[nsel * 5 + 4] = c.w;
            }
            __syncthreads();   // make selB/selA visible before next iteration
            ++nsel;
        }
    }
    // tail: batch index + zeros (reference emits zeros for invalid picks)
    for (int n = nsel + lane; n < POST_N; n += 64) {
        o[n * 5 + 0] = (float)b;
        o[n * 5 + 1] = 0.0f;
        o[n * 5 + 2] = 0.0f;
        o[n * 5 + 3] = 0.0f;
        o[n * 5 + 4] = 0.0f;
    }
}

// ---------------------------------------------------------------------------
extern "C" void kernel_launch(void* const* d_in, const int* in_sizes, int n_in,
                              void* d_out, int out_size, void* d_ws, size_t ws_size,
                              hipStream_t stream) {
    const float* scores = (const float*)d_in[0];
    const float4* deltas = (const float4*)d_in[1];
    float* out = (float*)d_out;

    // workspace layout
    unsigned long long* keysA = (unsigned long long*)d_ws;                 // 32*49104*8 = 12.57 MB
    unsigned long long* keysB = keysA + (size_t)NBATCH * A_TOTAL;          // 12.57 MB
    float4* boxes = (float4*)(keysB + (size_t)NBATCH * A_TOTAL);           // 32*6000*16 = 3.07 MB
    float* areas = (float*)(boxes + (size_t)NBATCH * PRE_N);               // 0.77 MB

    int totalK = NBATCH * A_TOTAL;
    build_keys<<<(totalK + 255) / 256, 256, 0, stream>>>(scores, keysA);

    // 12 x 4-bit LSD passes over the 48-bit key; even count => result in keysA
    for (int pass = 0; pass < 12; ++pass) {
        const unsigned long long* src = (pass & 1) ? keysB : keysA;
        unsigned long long* dst = (pass & 1) ? keysA : keysB;
        radix_pass<<<NBATCH, RT, 0, stream>>>(src, dst, pass * 4);
    }

    int totalD = NBATCH * PRE_N;
    decode_topk<<<(totalD + 255) / 256, 256, 0, stream>>>(keysA, deltas, boxes, areas);

    nms_kernel<<<NBATCH, 64, 0, stream>>>(boxes, areas, out);
}

// Round 2
// 384.721 us; speedup vs baseline: 2.2847x; 2.2847x over previous
//
#include <hip/hip_runtime.h>

#define NBATCH 32
#define A_TOTAL 49104
#define PRE_N 6000
#define POST_N 300
#define NMS_T 0.7f
#define IMGF 512.0f
#define HB 4096           // score histogram buckets
#define CAP 7168          // compacted candidates capacity per batch (=256*28)
#define K_NMS 1024        // candidates covered by the parallel IoU bitmask
#define WPR 16            // 64-bit words per mask row (K_NMS/64)

// ---------------------------------------------------------------------------
// zero helper (d_ws is poisoned 0xAA and never re-poisoned between replays)
// ---------------------------------------------------------------------------
__global__ __launch_bounds__(256) void zero_u32(unsigned int* __restrict__ p, int n) {
    int i = blockIdx.x * 256 + threadIdx.x;
    if (i < n) p[i] = 0u;
}

// ---------------------------------------------------------------------------
// Per-batch histogram of quantized scores. 8 blocks per batch, LDS partials.
// bucket = floor(score*4096), clamped — monotone in score.
// ---------------------------------------------------------------------------
__global__ __launch_bounds__(256) void score_hist(const float* __restrict__ scores,
                                                  unsigned int* __restrict__ hist) {
    int b = blockIdx.x >> 3, part = blockIdx.x & 7;
    __shared__ unsigned int h[HB];
    for (int i = threadIdx.x; i < HB; i += 256) h[i] = 0u;
    __syncthreads();
    const int per = (A_TOTAL + 7) / 8;
    int s0 = part * per, s1 = min(s0 + per, A_TOTAL);
    const float* __restrict__ sc = scores + (size_t)b * A_TOTAL;
    for (int i = s0 + threadIdx.x; i < s1; i += 256) {
        float s = sc[i];
        int q = (int)(s * 4096.0f);
        q = max(0, min(HB - 1, q));
        atomicAdd(&h[q], 1u);
    }
    __syncthreads();
    for (int i = threadIdx.x; i < HB; i += 256)
        if (h[i]) atomicAdd(&hist[(size_t)b * HB + i], h[i]);
}

// ---------------------------------------------------------------------------
// Find per-batch threshold bucket T = largest T with suffix-count >= PRE_N.
// ---------------------------------------------------------------------------
__global__ __launch_bounds__(256) void find_thresh(const unsigned int* __restrict__ hist,
                                                   int* __restrict__ thr) {
    int b = blockIdx.x, t = threadIdx.x;
    __shared__ unsigned int bs[256];
    const unsigned int* __restrict__ h = hist + (size_t)b * HB;
    unsigned int s = 0;
#pragma unroll
    for (int q = 0; q < 16; ++q) s += h[t * 16 + q];
    bs[t] = s;
    __syncthreads();
    if (t == 0) {
        unsigned int acc = 0;
        int c = 255;
        for (; c >= 0; --c) {
            if (acc + bs[c] >= PRE_N) break;
            acc += bs[c];
        }
        if (c < 0) c = 0;
        int qq;
        for (qq = c * 16 + 15; qq >= c * 16; --qq) {
            acc += h[qq];
            if (acc >= PRE_N) break;
        }
        if (qq < c * 16) qq = c * 16;
        thr[b] = qq;
    }
}

// ---------------------------------------------------------------------------
// Compact candidates with bucket >= T into compact[b][*] (unordered — the
// LDS sort fixes order). Wave-aggregated atomics: one atomicAdd per wave.
// key = (score_bits << 16) | (65535 - idx): ascending sort == top_k order
// reversed, ties -> lower index first.
// ---------------------------------------------------------------------------
__global__ __launch_bounds__(256) void compact_keys(const float* __restrict__ scores,
                                                    const int* __restrict__ thr,
                                                    unsigned int* __restrict__ cntg,
                                                    unsigned long long* __restrict__ compact) {
    int b = blockIdx.x >> 3, part = blockIdx.x & 7;
    int T = thr[b];
    const int per = (A_TOTAL + 7) / 8;
    int s0 = part * per, s1 = min(s0 + per, A_TOTAL);
    const float* __restrict__ sc = scores + (size_t)b * A_TOTAL;
    int lane = threadIdx.x & 63;
    for (int i = s0 + threadIdx.x; i < s1; i += 256) {
        float s = sc[i];
        int q = (int)(s * 4096.0f);
        q = max(0, min(HB - 1, q));
        bool sel = (q >= T);
        unsigned long long m = __ballot(sel);
        unsigned int base = 0;
        unsigned int nsel = (unsigned int)__popcll(m);
        if (lane == 0 && nsel) base = atomicAdd(&cntg[b], nsel);
        base = __shfl(base, 0);
        unsigned int off = (unsigned int)__popcll(m & ((1ULL << lane) - 1ULL));
        if (sel) {
            unsigned int pos = base + off;
            if (pos < CAP) {
                unsigned long long key =
                    ((unsigned long long)__float_as_uint(s) << 16) |
                    (unsigned long long)(65535 - i);
                compact[(size_t)b * CAP + pos] = key;
            }
        }
    }
}

// ---------------------------------------------------------------------------
// Full LDS-resident stable LSD radix sort (12 x 4-bit) of CAP elements per
// batch (padding key=0 sorts to the front). Writes ord[b][r] = anchor idx of
// r-th highest score. One block per batch, 129 KB LDS.
// ---------------------------------------------------------------------------
__global__ __launch_bounds__(256) void sort_compact(const unsigned long long* __restrict__ compact,
                                                    const unsigned int* __restrict__ cntg,
                                                    int* __restrict__ ord) {
    __shared__ unsigned long long bufA[CAP];
    __shared__ unsigned long long bufB[CAP];
    __shared__ unsigned int cnt[16 * 256];   // digit-major: cnt[d*256 + t]
    __shared__ unsigned int sums[256];
    int b = blockIdx.x, t = threadIdx.x;
    unsigned int M = cntg[b];
    if (M > CAP) M = CAP;
    const unsigned long long* __restrict__ src = compact + (size_t)b * CAP;
    for (int i = t; i < CAP; i += 256) bufA[i] = (i < (int)M) ? src[i] : 0ULL;
    __syncthreads();

    unsigned long long* sb = bufA;
    unsigned long long* db = bufB;
    const int start = t * (CAP / 256);   // 28 contiguous elements per thread
    for (int pass = 0; pass < 12; ++pass) {
        int shift = pass * 4;
#pragma unroll
        for (int d = 0; d < 16; ++d) cnt[d * 256 + t] = 0u;
        // own-column histogram: no barrier needed between zero and count
        for (int i = start; i < start + CAP / 256; ++i) {
            int dig = (int)((sb[i] >> shift) & 15ULL);
            cnt[dig * 256 + t] += 1u;
        }
        __syncthreads();
        // exclusive scan of the 4096 counters in memory-linear order
        unsigned int vals[16];
        unsigned int run = 0;
#pragma unroll
        for (int q = 0; q < 16; ++q) vals[q] = cnt[t * 16 + q];
#pragma unroll
        for (int q = 0; q < 16; ++q) { unsigned int v = vals[q]; vals[q] = run; run += v; }
        sums[t] = run;
        unsigned int total = run;
        __syncthreads();
        for (int st = 1; st < 256; st <<= 1) {
            unsigned int v = 0;
            if (t >= st) v = sums[t - st];
            __syncthreads();
            sums[t] += v;
            __syncthreads();
        }
        unsigned int base = sums[t] - total;
#pragma unroll
        for (int q = 0; q < 16; ++q) cnt[t * 16 + q] = vals[q] + base;
        __syncthreads();
        // stable scatter
        for (int i = start; i < start + CAP / 256; ++i) {
            unsigned long long k = sb[i];
            int dig = (int)((k >> shift) & 15ULL);
            unsigned int pos = cnt[dig * 256 + t];
            cnt[dig * 256 + t] = pos + 1u;
            db[pos] = k;
        }
        __syncthreads();
        unsigned long long* tmp = sb; sb = db; db = tmp;
    }
    // 12 passes (even) -> result in bufA == sb. Top PRE_N read from the back.
    for (int r = t; r < PRE_N; r += 256) {
        unsigned long long k = sb[CAP - 1 - r];
        ord[(size_t)b * PRE_N + r] = 65535 - (int)(k & 0xFFFFULL);
    }
}

// ---------------------------------------------------------------------------
// Decode top PRE_N boxes per batch. Anchor regenerated in f64 then cast to
// f32 (matches numpy ANCHORS), then f32 decode mirroring reference op order.
// ---------------------------------------------------------------------------
__global__ __launch_bounds__(256) void decode_topk(const int* __restrict__ ord,
                                                   const float4* __restrict__ deltas,
                                                   float4* __restrict__ boxes,
                                                   float* __restrict__ areas) {
    int gid = blockIdx.x * 256 + threadIdx.x;
    if (gid >= NBATCH * PRE_N) return;
    int b = gid / PRE_N;
    int idx = ord[gid];

    int off, fs, stride, size;
    if (idx < 36864)      { off = 0;     fs = 64; stride = 8;   size = 32;  }
    else if (idx < 46080) { off = 36864; fs = 32; stride = 16;  size = 64;  }
    else if (idx < 48384) { off = 46080; fs = 16; stride = 32;  size = 128; }
    else if (idx < 48960) { off = 48384; fs = 8;  stride = 64;  size = 256; }
    else                  { off = 48960; fs = 4;  stride = 128; size = 512; }
    int loc = idx - off;
    int p = loc / 9, k = loc % 9;
    int iy = p / fs, jx = p % fs;
    int ks = k % 3, kr = k / 3;

    double scale = pow(2.0, (double)ks / 3.0);
    double ratio = (kr == 0) ? 0.5 : (kr == 1 ? 1.0 : 2.0);
    double ss = (double)size * scale;
    double area0 = ss * ss;
    double w = sqrt(area0 / ratio);
    double h = w * ratio;
    double cxs = ((double)jx + 0.5) * (double)stride;
    double cys = ((double)iy + 0.5) * (double)stride;
    float x1a = (float)(cxs - 0.5 * w);
    float x2a = (float)(cxs + 0.5 * w);
    float y1a = (float)(cys - 0.5 * h);
    float y2a = (float)(cys + 0.5 * h);

    float wa = x2a - x1a;
    float ha = y2a - y1a;
    float cxa = x1a + 0.5f * wa;
    float cya = y1a + 0.5f * ha;
    float4 d = deltas[(size_t)b * A_TOTAL + idx];
    float dx = d.x * 0.1f, dy = d.y * 0.1f, dw = d.z * 0.2f, dh = d.w * 0.2f;
    float pcx = cxa + dx * wa;
    float pcy = cya + dy * ha;
    float pw = expf(dw) * wa;
    float ph = expf(dh) * ha;
    float bx1 = fminf(fmaxf(pcx - 0.5f * pw, 0.0f), IMGF);
    float by1 = fminf(fmaxf(pcy - 0.5f * ph, 0.0f), IMGF);
    float bx2 = fminf(fmaxf(pcx + 0.5f * pw, 0.0f), IMGF);
    float by2 = fminf(fmaxf(pcy + 0.5f * ph, 0.0f), IMGF);
    boxes[gid] = make_float4(bx1, by1, bx2, by2);
    areas[gid] = (bx2 - bx1) * (by2 - by1);
}

// ---------------------------------------------------------------------------
// IoU bitmask for the first K_NMS candidates: mask[b][i][w] bit j set iff
// IoU(i, 64w+j) > NMS_T and (64w+j) > i.
// ---------------------------------------------------------------------------
__global__ __launch_bounds__(64) void iou_mask(const float4* __restrict__ boxes,
                                               const float* __restrict__ areas,
                                               unsigned long long* __restrict__ mask) {
    int cb = blockIdx.x;        // column block (word index)
    int rb = blockIdx.y;        // row block
    int b = blockIdx.z;
    int tid = threadIdx.x;
    int i = rb * 64 + tid;
    size_t base = (size_t)b * PRE_N;
    size_t mrow = ((size_t)b * K_NMS + i) * WPR + cb;
    if (cb < rb) {              // every j in this word < i
        mask[mrow] = 0ULL;
        return;
    }
    __shared__ float4 cB[64];
    __shared__ float cA[64];
    int jg = cb * 64 + tid;
    cB[tid] = boxes[base + jg];
    cA[tid] = areas[base + jg];
    __syncthreads();
    float4 bi = boxes[base + i];
    float ai = areas[base + i];
    unsigned long long w = 0ULL;
    for (int jj = 0; jj < 64; ++jj) {
        int j = cb * 64 + jj;
        if (j > i) {
            float4 bj = cB[jj];
            float xx1 = fmaxf(bi.x, bj.x);
            float yy1 = fmaxf(bi.y, bj.y);
            float xx2 = fminf(bi.z, bj.z);
            float yy2 = fminf(bi.w, bj.w);
            float inter = fmaxf(xx2 - xx1, 0.0f) * fmaxf(yy2 - yy1, 0.0f);
            float iou = inter / (ai + cA[jj] - inter + 1e-8f);
            if (iou > NMS_T) w |= (1ULL << jj);
        }
    }
    mask[mrow] = w;
}

// ---------------------------------------------------------------------------
// Greedy NMS walk: one wave per batch. removed-bitmap lives in lanes 0..15's
// registers; mask rows prefetched one candidate ahead. Serial-wave fallback
// for i >= K_NMS (rare) keeps exactness.
// ---------------------------------------------------------------------------
__global__ __launch_bounds__(64) void nms_final(const float4* __restrict__ boxes,
                                                const float* __restrict__ areas,
                                                const unsigned long long* __restrict__ mask,
                                                float* __restrict__ out) {
    int b = blockIdx.x;
    int lane = threadIdx.x;
    const float4* __restrict__ bb = boxes + (size_t)b * PRE_N;
    const float* __restrict__ aa = areas + (size_t)b * PRE_N;
    float* __restrict__ o = out + (size_t)b * POST_N * 5;
    __shared__ float4 selB[POST_N];
    __shared__ float selA[POST_N];
    const unsigned long long* __restrict__ mrow = mask + (size_t)b * K_NMS * WPR;

    unsigned long long removed = 0ULL;
    int nsel = 0;
    unsigned long long pre = (lane < WPR) ? mrow[lane] : 0ULL;
    for (int i = 0; i < K_NMS && nsel < POST_N; ++i) {
        unsigned long long cur = pre;
        if (i + 1 < K_NMS)
            pre = (lane < WPR) ? mrow[(size_t)(i + 1) * WPR + lane] : 0ULL;
        unsigned long long rw = __shfl(removed, i >> 6);
        if (!((rw >> (i & 63)) & 1ULL)) {
            float4 c = bb[i];
            float ac = aa[i];
            if (lane < WPR) removed |= cur;
            if (lane == 0) {
                selB[nsel] = c;
                selA[nsel] = ac;
                o[nsel * 5 + 0] = (float)b;
                o[nsel * 5 + 1] = c.x;
                o[nsel * 5 + 2] = c.y;
                o[nsel * 5 + 3] = c.z;
                o[nsel * 5 + 4] = c.w;
            }
            ++nsel;
        }
    }
    __syncthreads();

    // fallback: serial wave NMS against selected set for candidates >= K_NMS
    for (int i = K_NMS; i < PRE_N && nsel < POST_N; ++i) {
        float4 c = bb[i];
        float ac = aa[i];
        bool sup = false;
        for (int base = 0; base < nsel && !sup; base += 64) {
            int ti = base + lane;
            bool over = false;
            if (ti < nsel) {
                float4 s = selB[ti];
                float xx1 = fmaxf(c.x, s.x);
                float yy1 = fmaxf(c.y, s.y);
                float xx2 = fminf(c.z, s.z);
                float yy2 = fminf(c.w, s.w);
                float inter = fmaxf(xx2 - xx1, 0.0f) * fmaxf(yy2 - yy1, 0.0f);
                float iou = inter / (ac + selA[ti] - inter + 1e-8f);
                over = iou > NMS_T;
            }
            if (__any(over)) sup = true;
        }
        if (!sup) {
            if (lane == 0) {
                selB[nsel] = c;
                selA[nsel] = ac;
                o[nsel * 5 + 0] = (float)b;
                o[nsel * 5 + 1] = c.x;
                o[nsel * 5 + 2] = c.y;
                o[nsel * 5 + 3] = c.z;
                o[nsel * 5 + 4] = c.w;
            }
            __syncthreads();
            ++nsel;
        }
    }
    // tail: batch index + zeros
    for (int n = nsel + lane; n < POST_N; n += 64) {
        o[n * 5 + 0] = (float)b;
        o[n * 5 + 1] = 0.0f;
        o[n * 5 + 2] = 0.0f;
        o[n * 5 + 3] = 0.0f;
        o[n * 5 + 4] = 0.0f;
    }
}

// ---------------------------------------------------------------------------
extern "C" void kernel_launch(void* const* d_in, const int* in_sizes, int n_in,
                              void* d_out, int out_size, void* d_ws, size_t ws_size,
                              hipStream_t stream) {
    const float* scores = (const float*)d_in[0];
    const float4* deltas = (const float4*)d_in[1];
    float* out = (float*)d_out;

    // workspace layout (11.2 MB total)
    unsigned char* w = (unsigned char*)d_ws;
    unsigned int* hist = (unsigned int*)w;                                   // 512 KB
    unsigned int* cntg = (unsigned int*)(w + 524288);                        // 128 B (contig after hist)
    int* thr = (int*)(w + 524288 + 128);                                     // 128 B
    unsigned long long* compact = (unsigned long long*)(w + 524544);         // 1.75 MB
    int* ord = (int*)(w + 524544 + 1835008);                                 // 768 KB
    float4* boxes = (float4*)(w + 3127552);                                  // 3 MB
    float* areas = (float*)(w + 3127552 + 3072000);                          // 768 KB
    unsigned long long* mask = (unsigned long long*)(w + 6967552);           // 4 MB

    zero_u32<<<(131104 + 255) / 256, 256, 0, stream>>>(hist, 131104);        // hist + cntg
    score_hist<<<NBATCH * 8, 256, 0, stream>>>(scores, hist);
    find_thresh<<<NBATCH, 256, 0, stream>>>(hist, thr);
    compact_keys<<<NBATCH * 8, 256, 0, stream>>>(scores, thr, cntg, compact);
    sort_compact<<<NBATCH, 256, 0, stream>>>(compact, cntg, ord);
    decode_topk<<<(NBATCH * PRE_N + 255) / 256, 256, 0, stream>>>(ord, deltas, boxes, areas);
    iou_mask<<<dim3(WPR, K_NMS / 64, NBATCH), 64, 0, stream>>>(boxes, areas, mask);
    nms_final<<<NBATCH, 64, 0, stream>>>(boxes, areas, mask, out);
}

// Round 3
// 234.957 us; speedup vs baseline: 3.7411x; 1.6374x over previous
//
#include <hip/hip_runtime.h>

#define NBATCH 32
#define A_TOTAL 49104
#define PRE_N 6000
#define POST_N 300
#define NMS_T 0.7f
#define IMGF 512.0f
#define HB 4096           // score histogram buckets
#define NPART 8           // partial-histogram blocks per batch
#define CAP 7424          // compacted candidates capacity per batch (=256*29)
#define CHUNK 29          // elements per thread in the LDS sort
#define K_NMS 1024        // candidates covered by the parallel IoU bitmask
#define WPR 16            // 64-bit words per mask row (K_NMS/64)

// ---------------------------------------------------------------------------
// Per-(batch,part) partial histogram of quantized scores. Plain stores, no
// global atomics, no pre-zero pass. bucket = floor(score*4096) (monotone).
// ---------------------------------------------------------------------------
__global__ __launch_bounds__(256) void score_hist(const float* __restrict__ scores,
                                                  unsigned int* __restrict__ histp) {
    int b = blockIdx.x >> 3, part = blockIdx.x & 7;
    __shared__ unsigned int h[HB];
    for (int i = threadIdx.x; i < HB; i += 256) h[i] = 0u;
    __syncthreads();
    const int per = (A_TOTAL + NPART - 1) / NPART;
    int s0 = part * per, s1 = min(s0 + per, A_TOTAL);
    const float* __restrict__ sc = scores + (size_t)b * A_TOTAL;
    for (int i = s0 + threadIdx.x; i < s1; i += 256) {
        float s = sc[i];
        int q = (int)(s * 4096.0f);
        q = max(0, min(HB - 1, q));
        atomicAdd(&h[q], 1u);
    }
    __syncthreads();
    unsigned int* __restrict__ dst = histp + ((size_t)b * NPART + part) * HB;
    for (int i = threadIdx.x; i < HB; i += 256) dst[i] = h[i];
}

// ---------------------------------------------------------------------------
// Sum partials, find per-batch threshold bucket T = largest T with
// suffix-count >= PRE_N. Also zeroes cntg (used by compact_keys).
// ---------------------------------------------------------------------------
__global__ __launch_bounds__(256) void find_thresh(const unsigned int* __restrict__ histp,
                                                   int* __restrict__ thr,
                                                   unsigned int* __restrict__ cntg) {
    int b = blockIdx.x, t = threadIdx.x;
    __shared__ unsigned int hfull[HB];
    __shared__ unsigned int bs[256];
    const unsigned int* __restrict__ h = histp + (size_t)b * NPART * HB;
    unsigned int s = 0;
#pragma unroll
    for (int q = 0; q < 16; ++q) {
        unsigned int v = 0;
#pragma unroll
        for (int p = 0; p < NPART; ++p) v += h[p * HB + t * 16 + q];
        hfull[t * 16 + q] = v;
        s += v;
    }
    bs[t] = s;
    __syncthreads();
    if (t == 0) {
        unsigned int acc = 0;
        int c = 255;
        for (; c >= 0; --c) {
            if (acc + bs[c] >= PRE_N) break;
            acc += bs[c];
        }
        if (c < 0) c = 0;
        int qq;
        for (qq = c * 16 + 15; qq >= c * 16; --qq) {
            acc += hfull[qq];
            if (acc >= PRE_N) break;
        }
        if (qq < c * 16) qq = c * 16;
        thr[b] = qq;
        cntg[b] = 0u;
    }
}

// ---------------------------------------------------------------------------
// Compact candidates with bucket >= T. Block-aggregated: per-thread count,
// shfl block scan, ONE atomicAdd per block (256 total — no contention).
// key = (score_bits << 16) | (65535 - idx): ascending sort == top_k order
// reversed, ties -> lower index first.
// ---------------------------------------------------------------------------
__global__ __launch_bounds__(256) void compact_keys(const float* __restrict__ scores,
                                                    const int* __restrict__ thr,
                                                    unsigned int* __restrict__ cntg,
                                                    unsigned long long* __restrict__ compact) {
    __shared__ unsigned int wsum[4];
    __shared__ unsigned int bbase;
    int b = blockIdx.x >> 3, part = blockIdx.x & 7;
    int t = threadIdx.x, lane = t & 63, wid = t >> 6;
    int T = thr[b];
    const int per = (A_TOTAL + NPART - 1) / NPART;
    int s0 = part * per, s1 = min(s0 + per, A_TOTAL);
    const float* __restrict__ sc = scores + (size_t)b * A_TOTAL;

    // phase 1: count selected in my (interleaved) slice
    unsigned int cnt = 0;
    for (int i = s0 + t; i < s1; i += 256) {
        int q = (int)(sc[i] * 4096.0f);
        q = max(0, min(HB - 1, q));
        cnt += (q >= T) ? 1u : 0u;
    }
    // wave inclusive scan
    unsigned int x = cnt;
    for (int d = 1; d < 64; d <<= 1) {
        unsigned int y = __shfl_up(x, d);
        if (lane >= d) x += y;
    }
    if (lane == 63) wsum[wid] = x;
    __syncthreads();
    unsigned int woff = 0;
#pragma unroll
    for (int w_ = 0; w_ < 4; ++w_) if (w_ < wid) woff += wsum[w_];
    unsigned int excl = woff + x - cnt;
    unsigned int btot = wsum[0] + wsum[1] + wsum[2] + wsum[3];
    if (t == 0) bbase = (btot > 0) ? atomicAdd(&cntg[b], btot) : 0u;
    __syncthreads();
    unsigned int pos = bbase + excl;
    // phase 2: re-walk (L2-hot) and write at deterministic offsets
    for (int i = s0 + t; i < s1; i += 256) {
        float s = sc[i];
        int q = (int)(s * 4096.0f);
        q = max(0, min(HB - 1, q));
        if (q >= T) {
            if (pos < CAP) {
                unsigned long long key =
                    ((unsigned long long)__float_as_uint(s) << 16) |
                    (unsigned long long)(65535 - i);
                compact[(size_t)b * CAP + pos] = key;
            }
            ++pos;
        }
    }
}

// ---------------------------------------------------------------------------
// LDS-resident stable LSD radix sort of CAP elements per batch, with dynamic
// pass skipping: digits with zero varying bits (AND==OR over real keys) are
// skipped. Padding zeros still sort to the front (real keys' low 16 bits are
// >= 16432, so real > padding under any performed-pass subset). All real keys
// are distinct (unique idx field), so stability only matters within the LSD
// invariant, preserved by contiguous per-thread chunks.
// ---------------------------------------------------------------------------
#define CSW(f) ((f) + ((f) >> 5))   // counter-array swizzle (kills 32-way conflicts)

__global__ __launch_bounds__(256) void sort_compact(const unsigned long long* __restrict__ compact,
                                                    const unsigned int* __restrict__ cntg,
                                                    int* __restrict__ ord) {
    __shared__ unsigned long long bufA[CAP];
    __shared__ unsigned long long bufB[CAP];
    __shared__ unsigned int cnt[4224];          // 4096 + swizzle pad
    __shared__ unsigned long long wredA[4], wredO[4];
    __shared__ unsigned int wsum[4];
    int b = blockIdx.x, t = threadIdx.x, lane = t & 63, wid = t >> 6;
    unsigned int M = cntg[b];
    if (M > CAP) M = CAP;
    const unsigned long long* __restrict__ src = compact + (size_t)b * CAP;

    unsigned long long myAnd = ~0ULL, myOr = 0ULL;
    for (int i = t; i < CAP; i += 256) {
        unsigned long long k = (i < (int)M) ? src[i] : 0ULL;
        bufA[i] = k;
        if (i < (int)M) { myAnd &= k; myOr |= k; }
    }
    for (int d = 1; d < 64; d <<= 1) {
        myAnd &= __shfl_xor(myAnd, d);
        myOr  |= __shfl_xor(myOr, d);
    }
    if (lane == 0) { wredA[wid] = myAnd; wredO[wid] = myOr; }
    __syncthreads();
    unsigned long long diff = (wredA[0] & wredA[1] & wredA[2] & wredA[3]) ^
                              (wredO[0] | wredO[1] | wredO[2] | wredO[3]);

    unsigned long long* sb = bufA;
    unsigned long long* db = bufB;
    const int start = t * CHUNK;
    for (int pass = 0; pass < 12; ++pass) {
        int shift = pass * 4;
        if (((diff >> shift) & 15ULL) == 0ULL) continue;   // uniform across block
        for (int i = t; i < 4224; i += 256) cnt[i] = 0u;
        __syncthreads();
        for (int i = start; i < start + CHUNK; ++i) {
            int dig = (int)((sb[i] >> shift) & 15ULL);
            cnt[CSW(dig * 256 + t)] += 1u;                 // own column — no race
        }
        __syncthreads();
        // scan the 4096 counters in digit-major order; thread t owns 16
        unsigned int vals[16];
        unsigned int run = 0;
#pragma unroll
        for (int q = 0; q < 16; ++q) vals[q] = cnt[CSW(t * 16 + q)];
#pragma unroll
        for (int q = 0; q < 16; ++q) { unsigned int v = vals[q]; vals[q] = run; run += v; }
        unsigned int x = run;
        for (int d = 1; d < 64; d <<= 1) {
            unsigned int y = __shfl_up(x, d);
            if (lane >= d) x += y;
        }
        if (lane == 63) wsum[wid] = x;
        __syncthreads();
        unsigned int woff = 0;
#pragma unroll
        for (int w_ = 0; w_ < 4; ++w_) if (w_ < wid) woff += wsum[w_];
        unsigned int base = woff + x - run;
#pragma unroll
        for (int q = 0; q < 16; ++q) cnt[CSW(t * 16 + q)] = vals[q] + base;
        __syncthreads();
        // stable scatter
        for (int i = start; i < start + CHUNK; ++i) {
            unsigned long long k = sb[i];
            int dig = (int)((k >> shift) & 15ULL);
            int f = CSW(dig * 256 + t);
            unsigned int pos = cnt[f];
            cnt[f] = pos + 1u;
            db[pos] = k;
        }
        __syncthreads();
        unsigned long long* tmp = sb; sb = db; db = tmp;
    }
    for (int r = t; r < PRE_N; r += 256) {
        unsigned long long k = sb[CAP - 1 - r];
        ord[(size_t)b * PRE_N + r] = 65535 - (int)(k & 0xFFFFULL);
    }
}

// ---------------------------------------------------------------------------
// Decode top PRE_N boxes per batch. Anchor regenerated in f64 then cast to
// f32 (matches numpy ANCHORS), then f32 decode mirroring reference op order.
// ---------------------------------------------------------------------------
__global__ __launch_bounds__(256) void decode_topk(const int* __restrict__ ord,
                                                   const float4* __restrict__ deltas,
                                                   float4* __restrict__ boxes,
                                                   float* __restrict__ areas) {
    int gid = blockIdx.x * 256 + threadIdx.x;
    if (gid >= NBATCH * PRE_N) return;
    int b = gid / PRE_N;
    int idx = ord[gid];

    int off, fs, stride, size;
    if (idx < 36864)      { off = 0;     fs = 64; stride = 8;   size = 32;  }
    else if (idx < 46080) { off = 36864; fs = 32; stride = 16;  size = 64;  }
    else if (idx < 48384) { off = 46080; fs = 16; stride = 32;  size = 128; }
    else if (idx < 48960) { off = 48384; fs = 8;  stride = 64;  size = 256; }
    else                  { off = 48960; fs = 4;  stride = 128; size = 512; }
    int loc = idx - off;
    int p = loc / 9, k = loc % 9;
    int iy = p / fs, jx = p % fs;
    int ks = k % 3, kr = k / 3;

    double scale = pow(2.0, (double)ks / 3.0);
    double ratio = (kr == 0) ? 0.5 : (kr == 1 ? 1.0 : 2.0);
    double ss = (double)size * scale;
    double area0 = ss * ss;
    double w = sqrt(area0 / ratio);
    double h = w * ratio;
    double cxs = ((double)jx + 0.5) * (double)stride;
    double cys = ((double)iy + 0.5) * (double)stride;
    float x1a = (float)(cxs - 0.5 * w);
    float x2a = (float)(cxs + 0.5 * w);
    float y1a = (float)(cys - 0.5 * h);
    float y2a = (float)(cys + 0.5 * h);

    float wa = x2a - x1a;
    float ha = y2a - y1a;
    float cxa = x1a + 0.5f * wa;
    float cya = y1a + 0.5f * ha;
    float4 d = deltas[(size_t)b * A_TOTAL + idx];
    float dx = d.x * 0.1f, dy = d.y * 0.1f, dw = d.z * 0.2f, dh = d.w * 0.2f;
    float pcx = cxa + dx * wa;
    float pcy = cya + dy * ha;
    float pw = expf(dw) * wa;
    float ph = expf(dh) * ha;
    float bx1 = fminf(fmaxf(pcx - 0.5f * pw, 0.0f), IMGF);
    float by1 = fminf(fmaxf(pcy - 0.5f * ph, 0.0f), IMGF);
    float bx2 = fminf(fmaxf(pcx + 0.5f * pw, 0.0f), IMGF);
    float by2 = fminf(fmaxf(pcy + 0.5f * ph, 0.0f), IMGF);
    boxes[gid] = make_float4(bx1, by1, bx2, by2);
    areas[gid] = (bx2 - bx1) * (by2 - by1);
}

// ---------------------------------------------------------------------------
// IoU bitmask for the first K_NMS candidates: mask[b][i][w] bit j set iff
// IoU(i, 64w+j) > NMS_T and (64w+j) > i.
// ---------------------------------------------------------------------------
__global__ __launch_bounds__(64) void iou_mask(const float4* __restrict__ boxes,
                                               const float* __restrict__ areas,
                                               unsigned long long* __restrict__ mask) {
    int cb = blockIdx.x;        // column block (word index)
    int rb = blockIdx.y;        // row block
    int b = blockIdx.z;
    int tid = threadIdx.x;
    int i = rb * 64 + tid;
    size_t base = (size_t)b * PRE_N;
    size_t mrow = ((size_t)b * K_NMS + i) * WPR + cb;
    if (cb < rb) {              // every j in this word < i
        mask[mrow] = 0ULL;
        return;
    }
    __shared__ float4 cB[64];
    __shared__ float cA[64];
    int jg = cb * 64 + tid;
    cB[tid] = boxes[base + jg];
    cA[tid] = areas[base + jg];
    __syncthreads();
    float4 bi = boxes[base + i];
    float ai = areas[base + i];
    unsigned long long w = 0ULL;
    for (int jj = 0; jj < 64; ++jj) {
        int j = cb * 64 + jj;
        if (j > i) {
            float4 bj = cB[jj];
            float xx1 = fmaxf(bi.x, bj.x);
            float yy1 = fmaxf(bi.y, bj.y);
            float xx2 = fminf(bi.z, bj.z);
            float yy2 = fminf(bi.w, bj.w);
            float inter = fmaxf(xx2 - xx1, 0.0f) * fmaxf(yy2 - yy1, 0.0f);
            float iou = inter / (ai + cA[jj] - inter + 1e-8f);
            if (iou > NMS_T) w |= (1ULL << jj);
        }
    }
    mask[mrow] = w;
}

// ---------------------------------------------------------------------------
// Greedy NMS walk: one wave per batch. removed-bitmap lives in lanes 0..15's
// registers; mask rows prefetched one candidate ahead. Serial-wave fallback
// for i >= K_NMS (rare) keeps exactness.
// ---------------------------------------------------------------------------
__global__ __launch_bounds__(64) void nms_final(const float4* __restrict__ boxes,
                                                const float* __restrict__ areas,
                                                const unsigned long long* __restrict__ mask,
                                                float* __restrict__ out) {
    int b = blockIdx.x;
    int lane = threadIdx.x;
    const float4* __restrict__ bb = boxes + (size_t)b * PRE_N;
    const float* __restrict__ aa = areas + (size_t)b * PRE_N;
    float* __restrict__ o = out + (size_t)b * POST_N * 5;
    __shared__ float4 selB[POST_N];
    __shared__ float selA[POST_N];
    const unsigned long long* __restrict__ mrow = mask + (size_t)b * K_NMS * WPR;

    unsigned long long removed = 0ULL;
    int nsel = 0;
    unsigned long long pre = (lane < WPR) ? mrow[lane] : 0ULL;
    for (int i = 0; i < K_NMS && nsel < POST_N; ++i) {
        unsigned long long cur = pre;
        if (i + 1 < K_NMS)
            pre = (lane < WPR) ? mrow[(size_t)(i + 1) * WPR + lane] : 0ULL;
        unsigned long long rw = __shfl(removed, i >> 6);
        if (!((rw >> (i & 63)) & 1ULL)) {
            float4 c = bb[i];
            float ac = aa[i];
            if (lane < WPR) removed |= cur;
            if (lane == 0) {
                selB[nsel] = c;
                selA[nsel] = ac;
                o[nsel * 5 + 0] = (float)b;
                o[nsel * 5 + 1] = c.x;
                o[nsel * 5 + 2] = c.y;
                o[nsel * 5 + 3] = c.z;
                o[nsel * 5 + 4] = c.w;
            }
            ++nsel;
        }
    }
    __syncthreads();

    // fallback: serial wave NMS against selected set for candidates >= K_NMS
    for (int i = K_NMS; i < PRE_N && nsel < POST_N; ++i) {
        float4 c = bb[i];
        float ac = aa[i];
        bool sup = false;
        for (int base = 0; base < nsel && !sup; base += 64) {
            int ti = base + lane;
            bool over = false;
            if (ti < nsel) {
                float4 s = selB[ti];
                float xx1 = fmaxf(c.x, s.x);
                float yy1 = fmaxf(c.y, s.y);
                float xx2 = fminf(c.z, s.z);
                float yy2 = fminf(c.w, s.w);
                float inter = fmaxf(xx2 - xx1, 0.0f) * fmaxf(yy2 - yy1, 0.0f);
                float iou = inter / (ac + selA[ti] - inter + 1e-8f);
                over = iou > NMS_T;
            }
            if (__any(over)) sup = true;
        }
        if (!sup) {
            if (lane == 0) {
                selB[nsel] = c;
                selA[nsel] = ac;
                o[nsel * 5 + 0] = (float)b;
                o[nsel * 5 + 1] = c.x;
                o[nsel * 5 + 2] = c.y;
                o[nsel * 5 + 3] = c.z;
                o[nsel * 5 + 4] = c.w;
            }
            __syncthreads();
            ++nsel;
        }
    }
    // tail: batch index + zeros
    for (int n = nsel + lane; n < POST_N; n += 64) {
        o[n * 5 + 0] = (float)b;
        o[n * 5 + 1] = 0.0f;
        o[n * 5 + 2] = 0.0f;
        o[n * 5 + 3] = 0.0f;
        o[n * 5 + 4] = 0.0f;
    }
}

// ---------------------------------------------------------------------------
extern "C" void kernel_launch(void* const* d_in, const int* in_sizes, int n_in,
                              void* d_out, int out_size, void* d_ws, size_t ws_size,
                              hipStream_t stream) {
    const float* scores = (const float*)d_in[0];
    const float4* deltas = (const float4*)d_in[1];
    float* out = (float*)d_out;

    // workspace layout (~14.9 MB)
    unsigned char* w = (unsigned char*)d_ws;
    unsigned int* histp = (unsigned int*)w;                                  // 4 MB
    int* thr = (int*)(w + 4194304);                                          // 128 B
    unsigned int* cntg = (unsigned int*)(w + 4194432);                       // 128 B
    unsigned long long* compact = (unsigned long long*)(w + 4194560);        // 1.9 MB
    int* ord = (int*)(w + 6095104);                                          // 768 KB
    float4* boxes = (float4*)(w + 6863104);                                  // 3 MB
    float* areas = (float*)(w + 9935104);                                    // 768 KB
    unsigned long long* mask = (unsigned long long*)(w + 10703104);          // 4 MB

    score_hist<<<NBATCH * NPART, 256, 0, stream>>>(scores, histp);
    find_thresh<<<NBATCH, 256, 0, stream>>>(histp, thr, cntg);
    compact_keys<<<NBATCH * NPART, 256, 0, stream>>>(scores, thr, cntg, compact);
    sort_compact<<<NBATCH, 256, 0, stream>>>(compact, cntg, ord);
    decode_topk<<<(NBATCH * PRE_N + 255) / 256, 256, 0, stream>>>(ord, deltas, boxes, areas);
    iou_mask<<<dim3(WPR, K_NMS / 64, NBATCH), 64, 0, stream>>>(boxes, areas, mask);
    nms_final<<<NBATCH, 64, 0, stream>>>(boxes, areas, mask, out);
}

// Round 4
// 121.066 us; speedup vs baseline: 7.2604x; 1.9407x over previous
//
#include <hip/hip_runtime.h>

#define NBATCH 32
#define A_TOTAL 49104
#define PRE_N 6000
#define POST_N 300
#define NMS_T 0.7f
#define IMGF 512.0f
#define HB 4096           // score histogram buckets
#define NPART 8           // partial-histogram blocks per batch
#define CAP 6400          // compacted candidates capacity per batch (=256*25)
#define CHUNK 25          // elements per thread in the LDS sort
#define K_NMS 1024        // candidates covered by the parallel IoU bitmask
#define NW 16             // 64-candidate words (K_NMS/64)

// ---------------------------------------------------------------------------
// Per-(batch,part) partial histogram of quantized scores. float4 loads, LDS
// atomics, plain stores (no global atomics, no pre-zero pass).
// ---------------------------------------------------------------------------
__global__ __launch_bounds__(256) void score_hist(const float* __restrict__ scores,
                                                  unsigned int* __restrict__ histp) {
    int b = blockIdx.x >> 3, part = blockIdx.x & 7;
    __shared__ unsigned int h[HB];
    for (int i = threadIdx.x; i < HB; i += 256) h[i] = 0u;
    __syncthreads();
    const int per = 6140;                       // multiple of 4; 8*6140 >= A_TOTAL
    int s0 = part * per, s1 = min(s0 + per, A_TOTAL);
    const float* __restrict__ sc = scores + (size_t)b * A_TOTAL;
    for (int i = s0 + threadIdx.x * 4; i < s1; i += 1024) {
        float4 v = *(const float4*)(sc + i);
#pragma unroll
        for (int e = 0; e < 4; ++e) {
            float s = (e == 0) ? v.x : (e == 1) ? v.y : (e == 2) ? v.z : v.w;
            int q = (int)(s * 4096.0f);
            q = max(0, min(HB - 1, q));
            atomicAdd(&h[q], 1u);
        }
    }
    __syncthreads();
    unsigned int* __restrict__ dst = histp + ((size_t)b * NPART + part) * HB;
    for (int i = threadIdx.x; i < HB; i += 256) dst[i] = h[i];
}

// ---------------------------------------------------------------------------
// Sum partials, find per-batch threshold bucket T = largest T with
// suffix-count >= PRE_N. Also zeroes cntg (used by compact_keys).
// ---------------------------------------------------------------------------
__global__ __launch_bounds__(256) void find_thresh(const unsigned int* __restrict__ histp,
                                                   int* __restrict__ thr,
                                                   unsigned int* __restrict__ cntg) {
    int b = blockIdx.x, t = threadIdx.x;
    __shared__ unsigned int hfull[HB];
    __shared__ unsigned int bs[256];
    const unsigned int* __restrict__ h = histp + (size_t)b * NPART * HB;
    unsigned int s = 0;
#pragma unroll
    for (int q = 0; q < 16; ++q) {
        unsigned int v = 0;
#pragma unroll
        for (int p = 0; p < NPART; ++p) v += h[p * HB + t * 16 + q];
        hfull[t * 16 + q] = v;
        s += v;
    }
    bs[t] = s;
    __syncthreads();
    if (t == 0) {
        unsigned int acc = 0;
        int c = 255;
        for (; c >= 0; --c) {
            if (acc + bs[c] >= PRE_N) break;
            acc += bs[c];
        }
        if (c < 0) c = 0;
        int qq;
        for (qq = c * 16 + 15; qq >= c * 16; --qq) {
            acc += hfull[qq];
            if (acc >= PRE_N) break;
        }
        if (qq < c * 16) qq = c * 16;
        thr[b] = qq;
        cntg[b] = 0u;
    }
}

// ---------------------------------------------------------------------------
// Compact candidates with bucket >= T. Block-aggregated: per-thread count,
// shfl block scan, ONE atomicAdd per block. float4 loads both phases.
// key = (score_bits << 16) | (65535 - idx): ascending sort == top_k order
// reversed, ties -> lower index first.
// ---------------------------------------------------------------------------
__global__ __launch_bounds__(256) void compact_keys(const float* __restrict__ scores,
                                                    const int* __restrict__ thr,
                                                    unsigned int* __restrict__ cntg,
                                                    unsigned long long* __restrict__ compact) {
    __shared__ unsigned int wsum[4];
    __shared__ unsigned int bbase;
    int b = blockIdx.x >> 3, part = blockIdx.x & 7;
    int t = threadIdx.x, lane = t & 63, wid = t >> 6;
    int T = thr[b];
    const int per = 6140;
    int s0 = part * per, s1 = min(s0 + per, A_TOTAL);
    const float* __restrict__ sc = scores + (size_t)b * A_TOTAL;

    // phase 1: count selected in my slice (float4)
    unsigned int cnt = 0;
    for (int i = s0 + t * 4; i < s1; i += 1024) {
        float4 v = *(const float4*)(sc + i);
#pragma unroll
        for (int e = 0; e < 4; ++e) {
            float s = (e == 0) ? v.x : (e == 1) ? v.y : (e == 2) ? v.z : v.w;
            int q = (int)(s * 4096.0f);
            q = max(0, min(HB - 1, q));
            cnt += (q >= T) ? 1u : 0u;
        }
    }
    // wave inclusive scan
    unsigned int x = cnt;
    for (int d = 1; d < 64; d <<= 1) {
        unsigned int y = __shfl_up(x, d);
        if (lane >= d) x += y;
    }
    if (lane == 63) wsum[wid] = x;
    __syncthreads();
    unsigned int woff = 0;
#pragma unroll
    for (int w_ = 0; w_ < 4; ++w_) if (w_ < wid) woff += wsum[w_];
    unsigned int excl = woff + x - cnt;
    unsigned int btot = wsum[0] + wsum[1] + wsum[2] + wsum[3];
    if (t == 0) bbase = (btot > 0) ? atomicAdd(&cntg[b], btot) : 0u;
    __syncthreads();
    unsigned int pos = bbase + excl;
    // phase 2: re-walk (L2-hot) and write at deterministic offsets
    for (int i = s0 + t * 4; i < s1; i += 1024) {
        float4 v = *(const float4*)(sc + i);
#pragma unroll
        for (int e = 0; e < 4; ++e) {
            float s = (e == 0) ? v.x : (e == 1) ? v.y : (e == 2) ? v.z : v.w;
            int q = (int)(s * 4096.0f);
            q = max(0, min(HB - 1, q));
            if (q >= T) {
                if (pos < CAP) {
                    unsigned long long key =
                        ((unsigned long long)__float_as_uint(s) << 16) |
                        (unsigned long long)(65535 - (i + e));
                    compact[(size_t)b * CAP + pos] = key;
                }
                ++pos;
            }
        }
    }
}

// ---------------------------------------------------------------------------
// LDS-resident stable LSD radix sort of CAP elements per batch, with dynamic
// pass skipping (digits with AND==OR over real keys are skipped; padding
// zeros sort to the front under any performed subset since real low-16 bits
// are >= 16432 > 0). Keys are distinct, chunks contiguous -> LSD invariant.
// ---------------------------------------------------------------------------
#define CSW(f) ((f) + ((f) >> 5))   // counter-array swizzle (kills 32-way conflicts)

__global__ __launch_bounds__(256) void sort_compact(const unsigned long long* __restrict__ compact,
                                                    const unsigned int* __restrict__ cntg,
                                                    int* __restrict__ ord) {
    __shared__ unsigned long long bufA[CAP];
    __shared__ unsigned long long bufB[CAP];
    __shared__ unsigned int cnt[4224];          // 4096 + swizzle pad
    __shared__ unsigned long long wredA[4], wredO[4];
    __shared__ unsigned int wsum[4];
    int b = blockIdx.x, t = threadIdx.x, lane = t & 63, wid = t >> 6;
    unsigned int M = cntg[b];
    if (M > CAP) M = CAP;
    const unsigned long long* __restrict__ src = compact + (size_t)b * CAP;

    unsigned long long myAnd = ~0ULL, myOr = 0ULL;
    for (int i = t; i < CAP; i += 256) {
        unsigned long long k = (i < (int)M) ? src[i] : 0ULL;
        bufA[i] = k;
        if (i < (int)M) { myAnd &= k; myOr |= k; }
    }
    for (int d = 1; d < 64; d <<= 1) {
        myAnd &= __shfl_xor(myAnd, d);
        myOr  |= __shfl_xor(myOr, d);
    }
    if (lane == 0) { wredA[wid] = myAnd; wredO[wid] = myOr; }
    __syncthreads();
    unsigned long long diff = (wredA[0] & wredA[1] & wredA[2] & wredA[3]) ^
                              (wredO[0] | wredO[1] | wredO[2] | wredO[3]);

    unsigned long long* sb = bufA;
    unsigned long long* db = bufB;
    const int start = t * CHUNK;
    for (int pass = 0; pass < 12; ++pass) {
        int shift = pass * 4;
        if (((diff >> shift) & 15ULL) == 0ULL) continue;   // uniform across block
        for (int i = t; i < 4224; i += 256) cnt[i] = 0u;
        __syncthreads();
        for (int i = start; i < start + CHUNK; ++i) {
            int dig = (int)((sb[i] >> shift) & 15ULL);
            cnt[CSW(dig * 256 + t)] += 1u;                 // own column — no race
        }
        __syncthreads();
        unsigned int vals[16];
        unsigned int run = 0;
#pragma unroll
        for (int q = 0; q < 16; ++q) vals[q] = cnt[CSW(t * 16 + q)];
#pragma unroll
        for (int q = 0; q < 16; ++q) { unsigned int v = vals[q]; vals[q] = run; run += v; }
        unsigned int x = run;
        for (int d = 1; d < 64; d <<= 1) {
            unsigned int y = __shfl_up(x, d);
            if (lane >= d) x += y;
        }
        if (lane == 63) wsum[wid] = x;
        __syncthreads();
        unsigned int woff = 0;
#pragma unroll
        for (int w_ = 0; w_ < 4; ++w_) if (w_ < wid) woff += wsum[w_];
        unsigned int base = woff + x - run;
#pragma unroll
        for (int q = 0; q < 16; ++q) cnt[CSW(t * 16 + q)] = vals[q] + base;
        __syncthreads();
        for (int i = start; i < start + CHUNK; ++i) {
            unsigned long long k = sb[i];
            int dig = (int)((k >> shift) & 15ULL);
            int f = CSW(dig * 256 + t);
            unsigned int pos = cnt[f];
            cnt[f] = pos + 1u;
            db[pos] = k;
        }
        __syncthreads();
        unsigned long long* tmp = sb; sb = db; db = tmp;
    }
    for (int r = t; r < PRE_N; r += 256) {
        unsigned long long k = sb[CAP - 1 - r];
        ord[(size_t)b * PRE_N + r] = 65535 - (int)(k & 0xFFFFULL);
    }
}

// ---------------------------------------------------------------------------
// Decode top PRE_N boxes per batch. Anchor regenerated in f64 then cast to
// f32 (matches numpy ANCHORS), then f32 decode mirroring reference op order.
// ---------------------------------------------------------------------------
__global__ __launch_bounds__(256) void decode_topk(const int* __restrict__ ord,
                                                   const float4* __restrict__ deltas,
                                                   float4* __restrict__ boxes,
                                                   float* __restrict__ areas) {
    int gid = blockIdx.x * 256 + threadIdx.x;
    if (gid >= NBATCH * PRE_N) return;
    int b = gid / PRE_N;
    int idx = ord[gid];

    int off, fs, stride, size;
    if (idx < 36864)      { off = 0;     fs = 64; stride = 8;   size = 32;  }
    else if (idx < 46080) { off = 36864; fs = 32; stride = 16;  size = 64;  }
    else if (idx < 48384) { off = 46080; fs = 16; stride = 32;  size = 128; }
    else if (idx < 48960) { off = 48384; fs = 8;  stride = 64;  size = 256; }
    else                  { off = 48960; fs = 4;  stride = 128; size = 512; }
    int loc = idx - off;
    int p = loc / 9, k = loc % 9;
    int iy = p / fs, jx = p % fs;
    int ks = k % 3, kr = k / 3;

    double scale = pow(2.0, (double)ks / 3.0);
    double ratio = (kr == 0) ? 0.5 : (kr == 1 ? 1.0 : 2.0);
    double ss = (double)size * scale;
    double area0 = ss * ss;
    double w = sqrt(area0 / ratio);
    double h = w * ratio;
    double cxs = ((double)jx + 0.5) * (double)stride;
    double cys = ((double)iy + 0.5) * (double)stride;
    float x1a = (float)(cxs - 0.5 * w);
    float x2a = (float)(cxs + 0.5 * w);
    float y1a = (float)(cys - 0.5 * h);
    float y2a = (float)(cys + 0.5 * h);

    float wa = x2a - x1a;
    float ha = y2a - y1a;
    float cxa = x1a + 0.5f * wa;
    float cya = y1a + 0.5f * ha;
    float4 d = deltas[(size_t)b * A_TOTAL + idx];
    float dx = d.x * 0.1f, dy = d.y * 0.1f, dw = d.z * 0.2f, dh = d.w * 0.2f;
    float pcx = cxa + dx * wa;
    float pcy = cya + dy * ha;
    float pw = expf(dw) * wa;
    float ph = expf(dh) * ha;
    float bx1 = fminf(fmaxf(pcx - 0.5f * pw, 0.0f), IMGF);
    float by1 = fminf(fmaxf(pcy - 0.5f * ph, 0.0f), IMGF);
    float bx2 = fminf(fmaxf(pcx + 0.5f * pw, 0.0f), IMGF);
    float by2 = fminf(fmaxf(pcy + 0.5f * ph, 0.0f), IMGF);
    boxes[gid] = make_float4(bx1, by1, bx2, by2);
    areas[gid] = (bx2 - bx1) * (by2 - by1);
}

// ---------------------------------------------------------------------------
// IoU bitmask, TRANSPOSED layout: maskT[b][wcol][i] = word wcol of row i
// (bit j set iff IoU(i, 64*wcol+j) > NMS_T and 64*wcol+j > i).
// Writes are coalesced over i (64 consecutive per block).
// ---------------------------------------------------------------------------
__global__ __launch_bounds__(64) void iou_mask(const float4* __restrict__ boxes,
                                               const float* __restrict__ areas,
                                               unsigned long long* __restrict__ maskT) {
    int cb = blockIdx.x;        // column word
    int rb = blockIdx.y;        // row block
    int b = blockIdx.z;
    int tid = threadIdx.x;
    int i = rb * 64 + tid;
    size_t base = (size_t)b * PRE_N;
    size_t midx = ((size_t)b * NW + cb) * K_NMS + i;
    if (cb < rb) {              // every j in this word < i
        maskT[midx] = 0ULL;
        return;
    }
    __shared__ float4 cB[64];
    __shared__ float cA[64];
    int jg = cb * 64 + tid;
    cB[tid] = boxes[base + jg];
    cA[tid] = areas[base + jg];
    __syncthreads();
    float4 bi = boxes[base + i];
    float ai = areas[base + i];
    unsigned long long w = 0ULL;
    for (int jj = 0; jj < 64; ++jj) {
        int j = cb * 64 + jj;
        if (j > i) {
            float4 bj = cB[jj];
            float xx1 = fmaxf(bi.x, bj.x);
            float yy1 = fmaxf(bi.y, bj.y);
            float xx2 = fminf(bi.z, bj.z);
            float yy2 = fminf(bi.w, bj.w);
            float inter = fmaxf(xx2 - xx1, 0.0f) * fmaxf(yy2 - yy1, 0.0f);
            float iou = inter / (ai + cA[jj] - inter + 1e-8f);
            if (iou > NMS_T) w |= (1ULL << jj);
        }
    }
    maskT[midx] = w;
}

// ---------------------------------------------------------------------------
// Word-parallel greedy NMS: one wave per batch, candidates in 16 groups of
// 64. Per group: OR-reduce lane partials -> alive; in-register 64x64 resolve
// (serial steps only for rows with nonzero within-word bits); picked lanes
// OR their row's later words into per-lane partials via coalesced loads.
// Identical semantics to the reference's sequential argmax scan.
// ---------------------------------------------------------------------------
__global__ __launch_bounds__(64) void nms_final(const float4* __restrict__ boxes,
                                                const float* __restrict__ areas,
                                                const unsigned long long* __restrict__ maskT,
                                                float* __restrict__ out) {
    int b = blockIdx.x;
    int lane = threadIdx.x;
    const float4* __restrict__ bb = boxes + (size_t)b * PRE_N;
    const float* __restrict__ aa = areas + (size_t)b * PRE_N;
    float* __restrict__ o = out + (size_t)b * POST_N * 5;
    __shared__ float4 selB[POST_N];
    __shared__ float selA[POST_N];
    const unsigned long long* __restrict__ T = maskT + (size_t)b * NW * K_NMS;

    unsigned long long part[NW];        // per-lane partial removed (static idx)
#pragma unroll
    for (int w = 0; w < NW; ++w) part[w] = 0ULL;
    int nsel = 0;                       // uniform across lanes

#pragma unroll
    for (int w = 0; w < NW; ++w) {
        if (nsel < POST_N) {
            // my row's within-word suppression bits (row w*64+lane, word w)
            unsigned long long Wj = T[(size_t)w * K_NMS + w * 64 + lane];
            // removed[w]: OR-reduce lane partials (uniform result)
            unsigned long long rem = part[w];
#pragma unroll
            for (int d = 32; d >= 1; d >>= 1) rem |= __shfl_xor(rem, d);
            unsigned long long alive = ~rem;
            // serial resolve over rows that suppress something in this word
            unsigned long long m = __ballot(Wj != 0ULL);
            while (m) {
                int i = __builtin_ctzll(m);
                m &= m - 1ULL;
                if ((alive >> i) & 1ULL) {          // uniform branch
                    unsigned long long wi = __shfl(Wj, i);
                    alive &= ~wi;                   // wi has only bits > i
                }
            }
            // emit picks (rank-capped), record for fallback
            bool mypick = (alive >> lane) & 1ULL;
            int myrank = nsel + (int)__popcll(alive & ((1ULL << lane) - 1ULL));
            if (mypick && myrank < POST_N) {
                int gi = w * 64 + lane;
                float4 c = bb[gi];
                float ac = aa[gi];
                selB[myrank] = c;
                selA[myrank] = ac;
                o[myrank * 5 + 0] = (float)b;
                o[myrank * 5 + 1] = c.x;
                o[myrank * 5 + 2] = c.y;
                o[myrank * 5 + 3] = c.z;
                o[myrank * 5 + 4] = c.w;
            }
            // cross-word suppression: coalesced loads (consecutive i per word)
            if (mypick) {
#pragma unroll
                for (int wc = w + 1; wc < NW; ++wc)
                    part[wc] |= T[(size_t)wc * K_NMS + w * 64 + lane];
            }
            nsel += (int)__popcll(alive);
        }
    }
    if (nsel > POST_N) nsel = POST_N;
    __syncthreads();

    // fallback: serial wave NMS against selected set for candidates >= K_NMS
    for (int i = K_NMS; i < PRE_N && nsel < POST_N; ++i) {
        float4 c = bb[i];
        float ac = aa[i];
        bool sup = false;
        for (int base2 = 0; base2 < nsel && !sup; base2 += 64) {
            int ti = base2 + lane;
            bool over = false;
            if (ti < nsel) {
                float4 s = selB[ti];
                float xx1 = fmaxf(c.x, s.x);
                float yy1 = fmaxf(c.y, s.y);
                float xx2 = fminf(c.z, s.z);
                float yy2 = fminf(c.w, s.w);
                float inter = fmaxf(xx2 - xx1, 0.0f) * fmaxf(yy2 - yy1, 0.0f);
                float iou = inter / (ac + selA[ti] - inter + 1e-8f);
                over = iou > NMS_T;
            }
            if (__any(over)) sup = true;
        }
        if (!sup) {
            if (lane == 0) {
                selB[nsel] = c;
                selA[nsel] = ac;
                o[nsel * 5 + 0] = (float)b;
                o[nsel * 5 + 1] = c.x;
                o[nsel * 5 + 2] = c.y;
                o[nsel * 5 + 3] = c.z;
                o[nsel * 5 + 4] = c.w;
            }
            __syncthreads();
            ++nsel;
        }
    }
    // tail: batch index + zeros
    for (int n = nsel + lane; n < POST_N; n += 64) {
        o[n * 5 + 0] = (float)b;
        o[n * 5 + 1] = 0.0f;
        o[n * 5 + 2] = 0.0f;
        o[n * 5 + 3] = 0.0f;
        o[n * 5 + 4] = 0.0f;
    }
}

// ---------------------------------------------------------------------------
extern "C" void kernel_launch(void* const* d_in, const int* in_sizes, int n_in,
                              void* d_out, int out_size, void* d_ws, size_t ws_size,
                              hipStream_t stream) {
    const float* scores = (const float*)d_in[0];
    const float4* deltas = (const float4*)d_in[1];
    float* out = (float*)d_out;

    // workspace layout (~14.6 MB)
    unsigned char* w = (unsigned char*)d_ws;
    unsigned int* histp = (unsigned int*)w;                                  // 4 MB
    int* thr = (int*)(w + 4194304);                                          // 128 B
    unsigned int* cntg = (unsigned int*)(w + 4194432);                       // 128 B
    unsigned long long* compact = (unsigned long long*)(w + 4194560);        // 1.6 MB
    int* ord = (int*)(w + 5832960);                                          // 768 KB
    float4* boxes = (float4*)(w + 6600960);                                  // 3 MB
    float* areas = (float*)(w + 9672960);                                    // 768 KB
    unsigned long long* maskT = (unsigned long long*)(w + 10440960);         // 4 MB

    score_hist<<<NBATCH * NPART, 256, 0, stream>>>(scores, histp);
    find_thresh<<<NBATCH, 256, 0, stream>>>(histp, thr, cntg);
    compact_keys<<<NBATCH * NPART, 256, 0, stream>>>(scores, thr, cntg, compact);
    sort_compact<<<NBATCH, 256, 0, stream>>>(compact, cntg, ord);
    decode_topk<<<(NBATCH * PRE_N + 255) / 256, 256, 0, stream>>>(ord, deltas, boxes, areas);
    iou_mask<<<dim3(NW, K_NMS / 64, NBATCH), 64, 0, stream>>>(boxes, areas, maskT);
    nms_final<<<NBATCH, 64, 0, stream>>>(boxes, areas, maskT, out);
}

// Round 5
// 93.140 us; speedup vs baseline: 9.4373x; 1.2998x over previous
//
#include <hip/hip_runtime.h>

#define NBATCH 32
#define A_TOTAL 49104
#define PRE_N 6000
#define POST_N 300
#define NMS_T 0.7f
#define IMGF 512.0f
#define HB 4096           // score histogram buckets
#define NPART 8           // partial-histogram blocks per batch
#define PER_PART 6140     // elements per part (multiple of 4; 8*6140 >= A_TOTAL)
#define CAP 6400          // compacted candidates capacity per batch
#define ST 512            // sort threads per block
#define SCH 13            // elements per sort thread (512*13 >= 6400)
#define K_NMS 1024        // candidates covered by the parallel IoU bitmask
#define NW 16             // 64-candidate words (K_NMS/64)
#define CSW(f) ((f) + ((f) >> 5))   // LDS counter swizzle

// ---------------------------------------------------------------------------
// Per-(batch,part) partial histogram of quantized scores. float4 loads, LDS
// atomics, plain stores (no global atomics, no pre-zero pass).
// ---------------------------------------------------------------------------
__global__ __launch_bounds__(256) void score_hist(const float* __restrict__ scores,
                                                  unsigned int* __restrict__ histp) {
    int b = blockIdx.x >> 3, part = blockIdx.x & 7;
    __shared__ unsigned int h[HB];
    for (int i = threadIdx.x; i < HB; i += 256) h[i] = 0u;
    __syncthreads();
    int s0 = part * PER_PART, s1 = min(s0 + PER_PART, A_TOTAL);
    const float* __restrict__ sc = scores + (size_t)b * A_TOTAL;
    for (int i = s0 + threadIdx.x * 4; i < s1; i += 1024) {
        float4 v = *(const float4*)(sc + i);
#pragma unroll
        for (int e = 0; e < 4; ++e) {
            float s = (e == 0) ? v.x : (e == 1) ? v.y : (e == 2) ? v.z : v.w;
            int q = (int)(s * 4096.0f);
            q = max(0, min(HB - 1, q));
            atomicAdd(&h[q], 1u);
        }
    }
    __syncthreads();
    unsigned int* __restrict__ dst = histp + ((size_t)b * NPART + part) * HB;
    for (int i = threadIdx.x; i < HB; i += 256) dst[i] = h[i];
}

// ---------------------------------------------------------------------------
// Sum partials -> threshold bucket T (largest T with suffix >= PRE_N), plus
// deterministic per-part bases (exclusive scan of per-part selected counts)
// and total M. No atomics downstream -> fully deterministic compact order.
// ---------------------------------------------------------------------------
__global__ __launch_bounds__(256) void find_thresh(const unsigned int* __restrict__ histp,
                                                   int* __restrict__ thr,
                                                   unsigned int* __restrict__ pbase) {
    int b = blockIdx.x, t = threadIdx.x, lane = t & 63, wid = t >> 6;
    __shared__ unsigned int hfull[HB];
    __shared__ unsigned int bs[256];
    __shared__ unsigned int partCnt[NPART];
    __shared__ int sT;
    const unsigned int* __restrict__ h = histp + (size_t)b * NPART * HB;
    unsigned int s = 0;
#pragma unroll
    for (int q = 0; q < 16; ++q) {
        unsigned int v = 0;
#pragma unroll
        for (int p = 0; p < NPART; ++p) v += h[p * HB + t * 16 + q];
        hfull[t * 16 + q] = v;
        s += v;
    }
    bs[t] = s;
    if (t < NPART) partCnt[t] = 0u;
    __syncthreads();
    if (t == 0) {
        unsigned int acc = 0;
        int c = 255;
        for (; c >= 0; --c) {
            if (acc + bs[c] >= PRE_N) break;
            acc += bs[c];
        }
        if (c < 0) c = 0;
        int qq;
        for (qq = c * 16 + 15; qq >= c * 16; --qq) {
            acc += hfull[qq];
            if (acc >= PRE_N) break;
        }
        if (qq < c * 16) qq = c * 16;
        thr[b] = qq;
        sT = qq;
    }
    __syncthreads();
    int T = sT;
    unsigned int sp0 = 0, sp1 = 0, sp2 = 0, sp3 = 0, sp4 = 0, sp5 = 0, sp6 = 0, sp7 = 0;
#pragma unroll
    for (int q = 0; q < 16; ++q) {
        int qq2 = t * 16 + q;
        if (qq2 >= T) {
            sp0 += h[0 * HB + qq2]; sp1 += h[1 * HB + qq2];
            sp2 += h[2 * HB + qq2]; sp3 += h[3 * HB + qq2];
            sp4 += h[4 * HB + qq2]; sp5 += h[5 * HB + qq2];
            sp6 += h[6 * HB + qq2]; sp7 += h[7 * HB + qq2];
        }
    }
#pragma unroll
    for (int d = 32; d >= 1; d >>= 1) {
        sp0 += __shfl_xor(sp0, d); sp1 += __shfl_xor(sp1, d);
        sp2 += __shfl_xor(sp2, d); sp3 += __shfl_xor(sp3, d);
        sp4 += __shfl_xor(sp4, d); sp5 += __shfl_xor(sp5, d);
        sp6 += __shfl_xor(sp6, d); sp7 += __shfl_xor(sp7, d);
    }
    if (lane == 0) {
        atomicAdd(&partCnt[0], sp0); atomicAdd(&partCnt[1], sp1);
        atomicAdd(&partCnt[2], sp2); atomicAdd(&partCnt[3], sp3);
        atomicAdd(&partCnt[4], sp4); atomicAdd(&partCnt[5], sp5);
        atomicAdd(&partCnt[6], sp6); atomicAdd(&partCnt[7], sp7);
    }
    __syncthreads();
    if (t == 0) {
        unsigned int run = 0;
#pragma unroll
        for (int p = 0; p < NPART; ++p) { pbase[b * 9 + p] = run; run += partCnt[p]; }
        pbase[b * 9 + 8] = run;   // M
    }
    (void)wid;
}

// ---------------------------------------------------------------------------
// Compact candidates with bucket >= T into idx-ORDERED position (deterministic
// part bases + contiguous per-thread ranges + block scan; NO atomics).
// key = ~score_bits (ascending == score descending); payload = anchor idx.
// Ties: equal keys keep idx order via stable sort => matches top_k.
// ---------------------------------------------------------------------------
__global__ __launch_bounds__(256) void compact_keys(const float* __restrict__ scores,
                                                    const int* __restrict__ thr,
                                                    const unsigned int* __restrict__ pbase,
                                                    unsigned int* __restrict__ ckey,
                                                    unsigned short* __restrict__ cpay) {
    __shared__ unsigned int wsum[4];
    int b = blockIdx.x >> 3, part = blockIdx.x & 7;
    int t = threadIdx.x, lane = t & 63, wid = t >> 6;
    int T = thr[b];
    int s0 = part * PER_PART;
    int lim = min(s0 + PER_PART, A_TOTAL);
    int myS = s0 + t * 24;
    int myE = min(myS + 24, lim);
    const float* __restrict__ sc = scores + (size_t)b * A_TOTAL;
    // phase 1: count selected in my contiguous range
    unsigned int cnt = 0;
    for (int i = myS; i < myE; i += 4) {
        float4 v = *(const float4*)(sc + i);
#pragma unroll
        for (int e = 0; e < 4; ++e) {
            float s = (e == 0) ? v.x : (e == 1) ? v.y : (e == 2) ? v.z : v.w;
            int q = (int)(s * 4096.0f);
            q = max(0, min(HB - 1, q));
            cnt += (q >= T) ? 1u : 0u;
        }
    }
    unsigned int x = cnt;
    for (int d = 1; d < 64; d <<= 1) {
        unsigned int y = __shfl_up(x, d);
        if (lane >= d) x += y;
    }
    if (lane == 63) wsum[wid] = x;
    __syncthreads();
    unsigned int woff = 0;
#pragma unroll
    for (int w_ = 0; w_ < 4; ++w_) if (w_ < wid) woff += wsum[w_];
    unsigned int pos = pbase[b * 9 + part] + woff + x - cnt;
    // phase 2: re-walk (L2-hot) and write at deterministic offsets
    for (int i = myS; i < myE; i += 4) {
        float4 v = *(const float4*)(sc + i);
#pragma unroll
        for (int e = 0; e < 4; ++e) {
            float s = (e == 0) ? v.x : (e == 1) ? v.y : (e == 2) ? v.z : v.w;
            int q = (int)(s * 4096.0f);
            q = max(0, min(HB - 1, q));
            if (q >= T) {
                if (pos < CAP) {
                    ckey[(size_t)b * CAP + pos] = ~__float_as_uint(s);
                    cpay[(size_t)b * CAP + pos] = (unsigned short)(i + e);
                }
                ++pos;
            }
        }
    }
}

// ---------------------------------------------------------------------------
// LDS-resident stable LSD radix sort of 32-bit keys + 16-bit payload.
// Register-packed per-thread counters (no LDS RMW chains), 512 threads,
// dynamic digit skip (uniform nibbles over real keys are skipped; padding
// 0xFFFFFFFF provably stays at the back: its sorted nibbles are max and
// stability keeps it behind on full ties). ord[b][r] = idx of rank r.
// ---------------------------------------------------------------------------
__global__ __launch_bounds__(ST) void sort_compact(const unsigned int* __restrict__ ckey,
                                                   const unsigned short* __restrict__ cpay,
                                                   const unsigned int* __restrict__ pbase,
                                                   int* __restrict__ ord) {
    __shared__ unsigned int kA[CAP], kB[CAP];
    __shared__ unsigned short pA[CAP], pB[CAP];
    __shared__ unsigned int cnt[CSW(16 * ST - 1) + 1];
    __shared__ unsigned int wsum[8];
    __shared__ unsigned int redA[8], redO[8];
    int b = blockIdx.x, t = threadIdx.x, lane = t & 63, wid = t >> 6;
    unsigned int M = pbase[b * 9 + 8];
    if (M > CAP) M = CAP;
    const unsigned int* __restrict__ gk = ckey + (size_t)b * CAP;
    const unsigned short* __restrict__ gp = cpay + (size_t)b * CAP;

    unsigned int myAnd = ~0u, myOr = 0u;
    for (int i = t; i < CAP; i += ST) {
        bool real = i < (int)M;
        unsigned int k = real ? gk[i] : 0xFFFFFFFFu;
        kA[i] = k;
        pA[i] = real ? gp[i] : (unsigned short)0;
        if (real) { myAnd &= k; myOr |= k; }
    }
#pragma unroll
    for (int d = 32; d >= 1; d >>= 1) {
        myAnd &= __shfl_xor(myAnd, d);
        myOr  |= __shfl_xor(myOr, d);
    }
    if (lane == 0) { redA[wid] = myAnd; redO[wid] = myOr; }
    __syncthreads();
    unsigned int dA = ~0u, dO = 0u;
#pragma unroll
    for (int w_ = 0; w_ < 8; ++w_) { dA &= redA[w_]; dO |= redO[w_]; }
    unsigned int diff = dA ^ dO;

    unsigned int* sK = kA; unsigned int* dK = kB;
    unsigned short* sP = pA; unsigned short* dP = pB;
    const int start = t * SCH;
    for (int pass = 0; pass < 8; ++pass) {
        int shift = pass * 4;
        if (((diff >> shift) & 15u) == 0u) continue;   // uniform across block
        // preload chunk keys into registers (static indices)
        unsigned int kr[SCH];
#pragma unroll
        for (int j = 0; j < SCH; ++j)
            kr[j] = (start + j < CAP) ? sK[start + j] : 0u;
        // histogram in 4 packed registers (4 x 8-bit fields)
        unsigned int pc0 = 0, pc1 = 0, pc2 = 0, pc3 = 0;
#pragma unroll
        for (int j = 0; j < SCH; ++j) {
            if (start + j < CAP) {
                unsigned int dg = (kr[j] >> shift) & 15u;
                unsigned int w = dg >> 2;
                unsigned int inc = 1u << ((dg & 3u) * 8u);
                pc0 += (w == 0u) ? inc : 0u;
                pc1 += (w == 1u) ? inc : 0u;
                pc2 += (w == 2u) ? inc : 0u;
                pc3 += (w == 3u) ? inc : 0u;
            }
        }
#pragma unroll
        for (int d = 0; d < 16; ++d) {
            unsigned int pcw = (d < 4) ? pc0 : (d < 8) ? pc1 : (d < 12) ? pc2 : pc3;
            cnt[CSW(d * ST + t)] = (pcw >> ((d & 3) * 8)) & 0xFFu;
        }
        __syncthreads();
        // exclusive scan of 8192 counters in digit-major linear order
        unsigned int vals[16];
        unsigned int run = 0;
#pragma unroll
        for (int q = 0; q < 16; ++q) vals[q] = cnt[CSW(t * 16 + q)];
#pragma unroll
        for (int q = 0; q < 16; ++q) { unsigned int v = vals[q]; vals[q] = run; run += v; }
        unsigned int x = run;
        for (int d = 1; d < 64; d <<= 1) {
            unsigned int y = __shfl_up(x, d);
            if (lane >= d) x += y;
        }
        if (lane == 63) wsum[wid] = x;
        __syncthreads();
        unsigned int woff = 0;
#pragma unroll
        for (int w_ = 0; w_ < 8; ++w_) if (w_ < wid) woff += wsum[w_];
        unsigned int base = woff + x - run;
#pragma unroll
        for (int q = 0; q < 16; ++q) cnt[CSW(t * 16 + q)] = vals[q] + base;
        __syncthreads();
        // stable scatter: prior-counts in packed registers, bases pure-read
        pc0 = pc1 = pc2 = pc3 = 0;
#pragma unroll
        for (int j = 0; j < SCH; ++j) {
            if (start + j < CAP) {
                unsigned int dg = (kr[j] >> shift) & 15u;
                unsigned int w = dg >> 2;
                unsigned int sh = (dg & 3u) * 8u;
                unsigned int pcw = (w == 0u) ? pc0 : (w == 1u) ? pc1 : (w == 2u) ? pc2 : pc3;
                unsigned int prior = (pcw >> sh) & 0xFFu;
                unsigned int pos = cnt[CSW((int)dg * ST + t)] + prior;
                unsigned int inc = 1u << sh;
                pc0 += (w == 0u) ? inc : 0u;
                pc1 += (w == 1u) ? inc : 0u;
                pc2 += (w == 2u) ? inc : 0u;
                pc3 += (w == 3u) ? inc : 0u;
                dK[pos] = kr[j];
                dP[pos] = sP[start + j];
            }
        }
        __syncthreads();
        unsigned int* tk = sK; sK = dK; dK = tk;
        unsigned short* tp = sP; sP = dP; dP = tp;
    }
    // ascending ~score == descending score: rank r at front
    for (int r = t; r < PRE_N; r += ST)
        ord[(size_t)b * PRE_N + r] = (int)sP[r];
}

// ---------------------------------------------------------------------------
// Decode top PRE_N boxes per batch. Anchor regenerated in f64 then cast to
// f32 (matches numpy ANCHORS), then f32 decode mirroring reference op order.
// ---------------------------------------------------------------------------
__global__ __launch_bounds__(256) void decode_topk(const int* __restrict__ ord,
                                                   const float4* __restrict__ deltas,
                                                   float4* __restrict__ boxes,
                                                   float* __restrict__ areas) {
    int gid = blockIdx.x * 256 + threadIdx.x;
    if (gid >= NBATCH * PRE_N) return;
    int b = gid / PRE_N;
    int idx = ord[gid];

    int off, fs, stride, size;
    if (idx < 36864)      { off = 0;     fs = 64; stride = 8;   size = 32;  }
    else if (idx < 46080) { off = 36864; fs = 32; stride = 16;  size = 64;  }
    else if (idx < 48384) { off = 46080; fs = 16; stride = 32;  size = 128; }
    else if (idx < 48960) { off = 48384; fs = 8;  stride = 64;  size = 256; }
    else                  { off = 48960; fs = 4;  stride = 128; size = 512; }
    int loc = idx - off;
    int p = loc / 9, k = loc % 9;
    int iy = p / fs, jx = p % fs;
    int ks = k % 3, kr = k / 3;

    double scale = pow(2.0, (double)ks / 3.0);
    double ratio = (kr == 0) ? 0.5 : (kr == 1 ? 1.0 : 2.0);
    double ss = (double)size * scale;
    double area0 = ss * ss;
    double w = sqrt(area0 / ratio);
    double h = w * ratio;
    double cxs = ((double)jx + 0.5) * (double)stride;
    double cys = ((double)iy + 0.5) * (double)stride;
    float x1a = (float)(cxs - 0.5 * w);
    float x2a = (float)(cxs + 0.5 * w);
    float y1a = (float)(cys - 0.5 * h);
    float y2a = (float)(cys + 0.5 * h);

    float wa = x2a - x1a;
    float ha = y2a - y1a;
    float cxa = x1a + 0.5f * wa;
    float cya = y1a + 0.5f * ha;
    float4 d = deltas[(size_t)b * A_TOTAL + idx];
    float dx = d.x * 0.1f, dy = d.y * 0.1f, dw = d.z * 0.2f, dh = d.w * 0.2f;
    float pcx = cxa + dx * wa;
    float pcy = cya + dy * ha;
    float pw = expf(dw) * wa;
    float ph = expf(dh) * ha;
    float bx1 = fminf(fmaxf(pcx - 0.5f * pw, 0.0f), IMGF);
    float by1 = fminf(fmaxf(pcy - 0.5f * ph, 0.0f), IMGF);
    float bx2 = fminf(fmaxf(pcx + 0.5f * pw, 0.0f), IMGF);
    float by2 = fminf(fmaxf(pcy + 0.5f * ph, 0.0f), IMGF);
    boxes[gid] = make_float4(bx1, by1, bx2, by2);
    areas[gid] = (bx2 - bx1) * (by2 - by1);
}

// ---------------------------------------------------------------------------
// IoU bitmask, TRANSPOSED layout: maskT[b][wcol][i] = word wcol of row i
// (bit j set iff IoU(i, 64*wcol+j) > NMS_T and 64*wcol+j > i).
// ---------------------------------------------------------------------------
__global__ __launch_bounds__(64) void iou_mask(const float4* __restrict__ boxes,
                                               const float* __restrict__ areas,
                                               unsigned long long* __restrict__ maskT) {
    int cb = blockIdx.x;        // column word
    int rb = blockIdx.y;        // row block
    int b = blockIdx.z;
    int tid = threadIdx.x;
    int i = rb * 64 + tid;
    size_t base = (size_t)b * PRE_N;
    size_t midx = ((size_t)b * NW + cb) * K_NMS + i;
    if (cb < rb) {              // every j in this word < i
        maskT[midx] = 0ULL;
        return;
    }
    __shared__ float4 cB[64];
    __shared__ float cA[64];
    int jg = cb * 64 + tid;
    cB[tid] = boxes[base + jg];
    cA[tid] = areas[base + jg];
    __syncthreads();
    float4 bi = boxes[base + i];
    float ai = areas[base + i];
    unsigned long long w = 0ULL;
    for (int jj = 0; jj < 64; ++jj) {
        int j = cb * 64 + jj;
        if (j > i) {
            float4 bj = cB[jj];
            float xx1 = fmaxf(bi.x, bj.x);
            float yy1 = fmaxf(bi.y, bj.y);
            float xx2 = fminf(bi.z, bj.z);
            float yy2 = fminf(bi.w, bj.w);
            float inter = fmaxf(xx2 - xx1, 0.0f) * fmaxf(yy2 - yy1, 0.0f);
            float iou = inter / (ai + cA[jj] - inter + 1e-8f);
            if (iou > NMS_T) w |= (1ULL << jj);
        }
    }
    maskT[midx] = w;
}

// ---------------------------------------------------------------------------
// Word-parallel greedy NMS (identical semantics to reference argmax scan).
// ---------------------------------------------------------------------------
__global__ __launch_bounds__(64) void nms_final(const float4* __restrict__ boxes,
                                                const float* __restrict__ areas,
                                                const unsigned long long* __restrict__ maskT,
                                                float* __restrict__ out) {
    int b = blockIdx.x;
    int lane = threadIdx.x;
    const float4* __restrict__ bb = boxes + (size_t)b * PRE_N;
    const float* __restrict__ aa = areas + (size_t)b * PRE_N;
    float* __restrict__ o = out + (size_t)b * POST_N * 5;
    __shared__ float4 selB[POST_N];
    __shared__ float selA[POST_N];
    const unsigned long long* __restrict__ T = maskT + (size_t)b * NW * K_NMS;

    unsigned long long part[NW];
#pragma unroll
    for (int w = 0; w < NW; ++w) part[w] = 0ULL;
    int nsel = 0;

#pragma unroll
    for (int w = 0; w < NW; ++w) {
        if (nsel < POST_N) {
            unsigned long long Wj = T[(size_t)w * K_NMS + w * 64 + lane];
            unsigned long long rem = part[w];
#pragma unroll
            for (int d = 32; d >= 1; d >>= 1) rem |= __shfl_xor(rem, d);
            unsigned long long alive = ~rem;
            unsigned long long m = __ballot(Wj != 0ULL);
            while (m) {
                int i = __builtin_ctzll(m);
                m &= m - 1ULL;
                if ((alive >> i) & 1ULL) {
                    unsigned long long wi = __shfl(Wj, i);
                    alive &= ~wi;
                }
            }
            bool mypick = (alive >> lane) & 1ULL;
            int myrank = nsel + (int)__popcll(alive & ((1ULL << lane) - 1ULL));
            if (mypick && myrank < POST_N) {
                int gi = w * 64 + lane;
                float4 c = bb[gi];
                float ac = aa[gi];
                selB[myrank] = c;
                selA[myrank] = ac;
                o[myrank * 5 + 0] = (float)b;
                o[myrank * 5 + 1] = c.x;
                o[myrank * 5 + 2] = c.y;
                o[myrank * 5 + 3] = c.z;
                o[myrank * 5 + 4] = c.w;
            }
            if (mypick) {
#pragma unroll
                for (int wc = w + 1; wc < NW; ++wc)
                    part[wc] |= T[(size_t)wc * K_NMS + w * 64 + lane];
            }
            nsel += (int)__popcll(alive);
        }
    }
    if (nsel > POST_N) nsel = POST_N;
    __syncthreads();

    // fallback: serial wave NMS for candidates >= K_NMS (rarely triggered)
    for (int i = K_NMS; i < PRE_N && nsel < POST_N; ++i) {
        float4 c = bb[i];
        float ac = aa[i];
        bool sup = false;
        for (int base2 = 0; base2 < nsel && !sup; base2 += 64) {
            int ti = base2 + lane;
            bool over = false;
            if (ti < nsel) {
                float4 s = selB[ti];
                float xx1 = fmaxf(c.x, s.x);
                float yy1 = fmaxf(c.y, s.y);
                float xx2 = fminf(c.z, s.z);
                float yy2 = fminf(c.w, s.w);
                float inter = fmaxf(xx2 - xx1, 0.0f) * fmaxf(yy2 - yy1, 0.0f);
                float iou = inter / (ac + selA[ti] - inter + 1e-8f);
                over = iou > NMS_T;
            }
            if (__any(over)) sup = true;
        }
        if (!sup) {
            if (lane == 0) {
                selB[nsel] = c;
                selA[nsel] = ac;
                o[nsel * 5 + 0] = (float)b;
                o[nsel * 5 + 1] = c.x;
                o[nsel * 5 + 2] = c.y;
                o[nsel * 5 + 3] = c.z;
                o[nsel * 5 + 4] = c.w;
            }
            __syncthreads();
            ++nsel;
        }
    }
    // tail: batch index + zeros
    for (int n = nsel + lane; n < POST_N; n += 64) {
        o[n * 5 + 0] = (float)b;
        o[n * 5 + 1] = 0.0f;
        o[n * 5 + 2] = 0.0f;
        o[n * 5 + 3] = 0.0f;
        o[n * 5 + 4] = 0.0f;
    }
}

// ---------------------------------------------------------------------------
extern "C" void kernel_launch(void* const* d_in, const int* in_sizes, int n_in,
                              void* d_out, int out_size, void* d_ws, size_t ws_size,
                              hipStream_t stream) {
    const float* scores = (const float*)d_in[0];
    const float4* deltas = (const float4*)d_in[1];
    float* out = (float*)d_out;

    // workspace layout (~14.2 MB)
    unsigned char* w = (unsigned char*)d_ws;
    unsigned int* histp = (unsigned int*)w;                                  // 4 MB
    int* thr = (int*)(w + 4194304);                                          // 128 B
    unsigned int* pbase = (unsigned int*)(w + 4194432);                      // 32*9*4 -> 2 KB
    unsigned int* ckey = (unsigned int*)(w + 4196480);                       // 800 KB
    unsigned short* cpay = (unsigned short*)(w + 5015680);                   // 400 KB
    int* ord = (int*)(w + 5425280);                                          // 750 KB
    float4* boxes = (float4*)(w + 6193280);                                  // 3 MB
    float* areas = (float*)(w + 9265280);                                    // 750 KB
    unsigned long long* maskT = (unsigned long long*)(w + 10033280);         // 4 MB

    score_hist<<<NBATCH * NPART, 256, 0, stream>>>(scores, histp);
    find_thresh<<<NBATCH, 256, 0, stream>>>(histp, thr, pbase);
    compact_keys<<<NBATCH * NPART, 256, 0, stream>>>(scores, thr, pbase, ckey, cpay);
    sort_compact<<<NBATCH, ST, 0, stream>>>(ckey, cpay, pbase, ord);
    decode_topk<<<(NBATCH * PRE_N + 255) / 256, 256, 0, stream>>>(ord, deltas, boxes, areas);
    iou_mask<<<dim3(NW, K_NMS / 64, NBATCH), 64, 0, stream>>>(boxes, areas, maskT);
    nms_final<<<NBATCH, 64, 0, stream>>>(boxes, areas, maskT, out);
}